// Round 3
// baseline (1306.157 us; speedup 1.0000x reference)
//
#include <hip/hip_runtime.h>
#include <hip/hip_bf16.h>

#define B_   4
#define CIN  64
#define HID  256
#define COUT 64
#define T_   16
#define H_   64
#define W_   64
#define HW_  (H_*W_)       // 4096
#define THW  (T_*HW_)      // 65536
#define EPS  1e-5f

typedef unsigned short ushort_t;
typedef unsigned int   uint_t;

// ---- stats live in static device memory (NOT d_ws) ---------------------------
#define SM1   0
#define SIS1  1024
#define SM2   2048
#define SIS2  3072
#define SM3   4096
#define SIS3  5120
#define SSES  6144
#define SAL   7168
#define SBE   8192
#define SMP   9216
#define SISP  9472
__device__ float g_stats[10240];

__device__ __forceinline__ float bf2f(ushort_t u) {
    return __uint_as_float(((uint_t)u) << 16);
}
__device__ __forceinline__ ushort_t f2bf(float f) {
    uint_t u = __float_as_uint(f);
    uint_t r = u + 0x7fffu + ((u >> 16) & 1u);   // round-to-nearest-even
    return (ushort_t)(r >> 16);
}

// ---------------- expand 1x1: x[gb,64,thw] (f32) -> h1[bb,256,thw] (bf16) -----
__global__ __launch_bounds__(256) void k_expand(const float* __restrict__ x,
                                                const float* __restrict__ w1,
                                                ushort_t* __restrict__ h1, int b0) {
    __shared__ float wl[HID*CIN];                 // 64 KB
    const int tid = threadIdx.x;
    const int bb  = blockIdx.y;
    const int gb  = b0 + bb;
    const int pos = blockIdx.x * 256 + tid;

    #pragma unroll
    for (int i = 0; i < HID*CIN/256; ++i) {       // 64 per thread, coalesced
        int idx = i*256 + tid;
        wl[idx] = w1[idx];
    }

    float xr[CIN];
    #pragma unroll
    for (int c = 0; c < CIN; ++c)
        xr[c] = x[(size_t)(gb*CIN + c) * THW + pos];
    __syncthreads();

    const size_t obase = (size_t)bb * HID * THW + pos;
    for (int o = 0; o < HID; ++o) {
        float a0 = 0.f;
        const float4* wv = (const float4*)(&wl[o*CIN]);
        #pragma unroll
        for (int c4 = 0; c4 < CIN/4; ++c4) {
            float4 wq = wv[c4];
            a0 = fmaf(wq.x, xr[c4*4+0], a0);
            a0 = fmaf(wq.y, xr[c4*4+1], a0);
            a0 = fmaf(wq.z, xr[c4*4+2], a0);
            a0 = fmaf(wq.w, xr[c4*4+3], a0);
        }
        h1[obase + (size_t)o * THW] = f2bf(a0);
    }
}

// ---------------- per-(bb,c) mean / inv_sd over THW, bf16 source --------------
__global__ __launch_bounds__(256) void k_stats_bf16(const ushort_t* __restrict__ src,
                                                    int moff, int isoff) {
    const int bc = blockIdx.x;
    const int tid = threadIdx.x;
    const ushort_t* p = src + (size_t)bc * THW;
    float s = 0.f, ss = 0.f;
    #pragma unroll 4
    for (int i = 0; i < THW/(256*8); ++i) {       // 32 iters, 16B/lane
        uint4 u = *(const uint4*)(p + i*2048 + tid*8);
        uint_t w[4] = {u.x, u.y, u.z, u.w};
        #pragma unroll
        for (int j = 0; j < 4; ++j) {
            float f0 = __uint_as_float(w[j] << 16);
            float f1 = __uint_as_float(w[j] & 0xffff0000u);
            s += f0; ss = fmaf(f0, f0, ss);
            s += f1; ss = fmaf(f1, f1, ss);
        }
    }
    #pragma unroll
    for (int off = 32; off > 0; off >>= 1) {
        s  += __shfl_down(s,  off, 64);
        ss += __shfl_down(ss, off, 64);
    }
    __shared__ float ls[4], lss[4];
    int wid = tid >> 6, lane = tid & 63;
    if (lane == 0) { ls[wid] = s; lss[wid] = ss; }
    __syncthreads();
    if (tid == 0) {
        float st  = ls[0]+ls[1]+ls[2]+ls[3];
        float sst = lss[0]+lss[1]+lss[2]+lss[3];
        float m = st * (1.f/THW);
        float v = sst * (1.f/THW) - m*m;
        g_stats[moff  + bc] = m;
        g_stats[isoff + bc] = 1.f / sqrtf(v + EPS);
    }
}

// ---------------- same, fp32 source (proj stats) ------------------------------
__global__ __launch_bounds__(256) void k_stats_f32(const float* __restrict__ src,
                                                   int moff, int isoff) {
    const int bc = blockIdx.x;
    const int tid = threadIdx.x;
    const float* p = src + (size_t)bc * THW;
    float s = 0.f, ss = 0.f;
    #pragma unroll 4
    for (int i = 0; i < THW/(256*4); ++i) {       // 64 iters
        float4 u = *(const float4*)(p + i*1024 + tid*4);
        s += u.x; ss = fmaf(u.x, u.x, ss);
        s += u.y; ss = fmaf(u.y, u.y, ss);
        s += u.z; ss = fmaf(u.z, u.z, ss);
        s += u.w; ss = fmaf(u.w, u.w, ss);
    }
    #pragma unroll
    for (int off = 32; off > 0; off >>= 1) {
        s  += __shfl_down(s,  off, 64);
        ss += __shfl_down(ss, off, 64);
    }
    __shared__ float ls[4], lss[4];
    int wid = tid >> 6, lane = tid & 63;
    if (lane == 0) { ls[wid] = s; lss[wid] = ss; }
    __syncthreads();
    if (tid == 0) {
        float st  = ls[0]+ls[1]+ls[2]+ls[3];
        float sst = lss[0]+lss[1]+lss[2]+lss[3];
        float m = st * (1.f/THW);
        float v = sst * (1.f/THW) - m*m;
        g_stats[moff  + bc] = m;
        g_stats[isoff + bc] = 1.f / sqrtf(v + EPS);
    }
}

// ------------ spatial dw 3x3 (+TIM fold, + stage1 norm/relu on the fly) -------
__global__ __launch_bounds__(256) void k_dws(const ushort_t* __restrict__ h1,
                                             const float* __restrict__ wdw,
                                             ushort_t* __restrict__ h2) {
    const int tx = threadIdx.x;                   // 0..63 (W)
    const int ty = threadIdx.y;                   // 0..3
    const int y  = blockIdx.x * 4 + ty;
    const int t  = blockIdx.y;
    const int bc = blockIdx.z;
    const int o  = bc & (HID-1);
    const size_t outidx = (size_t)bc * THW + t*HW_ + y*W_ + tx;

    // TIM: o<32 -> read t+1 (zero at t==15); 32<=o<64 -> zero; else identity
    int ts = t; bool zero = false;
    if (o < 32)       { ts = t + 1; if (ts >= T_) zero = true; }
    else if (o < 64)  { zero = true; }
    if (zero) { h2[outidx] = 0; return; }

    const float a  = g_stats[SIS1 + bc];
    const float bb = -g_stats[SM1 + bc] * a;
    const ushort_t* sp = h1 + (size_t)bc * THW + ts*HW_;

    float wf[9];
    #pragma unroll
    for (int k = 0; k < 9; ++k) wf[k] = wdw[o*9 + k];

    float acc = 0.f;
    #pragma unroll
    for (int dy = -1; dy <= 1; ++dy) {
        int yy = y + dy;
        if (yy < 0 || yy >= H_) continue;
        #pragma unroll
        for (int dx = -1; dx <= 1; ++dx) {
            int xx = tx + dx;
            if (xx < 0 || xx >= W_) continue;
            float v = fmaxf(fmaf(bf2f(sp[yy*W_ + xx]), a, bb), 0.f);
            acc = fmaf(wf[(dy+1)*3 + (dx+1)], v, acc);
        }
    }
    h2[outidx] = f2bf(acc);
}

// ------------ temporal dw 3 (+ stage2 norm/relu on the fly) -------------------
__global__ __launch_bounds__(256) void k_dwt(const ushort_t* __restrict__ h2,
                                             const float* __restrict__ wdt,
                                             ushort_t* __restrict__ h3) {
    const int tid = threadIdx.x;
    const int pos = blockIdx.x * 256 + tid;       // 0..4095 within slice
    const int t   = blockIdx.y;
    const int bc  = blockIdx.z;
    const int o   = bc & (HID-1);
    const float a  = g_stats[SIS2 + bc];
    const float bb = -g_stats[SM2 + bc] * a;
    const ushort_t* sp = h2 + (size_t)bc * THW;

    float acc = 0.f;
    #pragma unroll
    for (int dt = -1; dt <= 1; ++dt) {
        int tt = t + dt;
        if (tt < 0 || tt >= T_) continue;
        float v = fmaxf(fmaf(bf2f(sp[tt*HW_ + pos]), a, bb), 0.f);
        acc = fmaf(wdt[o*3 + dt + 1], v, acc);
    }
    h3[(size_t)bc*THW + t*HW_ + pos] = f2bf(acc);
}

// ------------ SE: per-(bb,c) mean of relu(norm3(h3)) --------------------------
__global__ __launch_bounds__(256) void k_semean(const ushort_t* __restrict__ h3) {
    const int bc = blockIdx.x;
    const int tid = threadIdx.x;
    const float a  = g_stats[SIS3 + bc];
    const float bb = -g_stats[SM3 + bc] * a;
    const ushort_t* p = h3 + (size_t)bc * THW;
    float s = 0.f;
    #pragma unroll 4
    for (int i = 0; i < THW/(256*8); ++i) {
        uint4 u = *(const uint4*)(p + i*2048 + tid*8);
        uint_t w[4] = {u.x, u.y, u.z, u.w};
        #pragma unroll
        for (int j = 0; j < 4; ++j) {
            s += fmaxf(fmaf(__uint_as_float(w[j] << 16),          a, bb), 0.f);
            s += fmaxf(fmaf(__uint_as_float(w[j] & 0xffff0000u),  a, bb), 0.f);
        }
    }
    #pragma unroll
    for (int off = 32; off > 0; off >>= 1) s += __shfl_down(s, off, 64);
    __shared__ float ls[4];
    int wid = tid >> 6, lane = tid & 63;
    if (lane == 0) ls[wid] = s;
    __syncthreads();
    if (tid == 0) g_stats[SSES + bc] = (ls[0]+ls[1]+ls[2]+ls[3]) * (1.f/THW);
}

// ------------ SE MLP -> fold sigmoid scale into proj's alpha/beta -------------
__global__ __launch_bounds__(256) void k_semlp(const float* __restrict__ wse1,
                                               const float* __restrict__ wse2) {
    __shared__ float mv[HID];
    __shared__ float y1[64];
    const int bb = blockIdx.x, tid = threadIdx.x;
    mv[tid] = g_stats[SSES + bb*HID + tid];
    __syncthreads();
    if (tid < 64) {
        float acc = 0.f;
        #pragma unroll 8
        for (int c = 0; c < HID; ++c) acc = fmaf(wse1[tid*HID + c], mv[c], acc);
        y1[tid] = fmaxf(acc, 0.f);
    }
    __syncthreads();
    float z = 0.f;
    #pragma unroll
    for (int c = 0; c < 64; ++c) z = fmaf(wse2[tid*64 + c], y1[c], z);
    float se = 1.f / (1.f + expf(-z));
    const int bc = bb*HID + tid;
    float al = g_stats[SIS3 + bc] * se;            // relu(norm)*se == max(0, h*al+be)
    g_stats[SAL + bc] = al;
    g_stats[SBE + bc] = -g_stats[SM3 + bc] * al;
}

// ------------ proj 1x1 (256->64), norm3+relu+SE folded into input -------------
__global__ __launch_bounds__(256) void k_proj(const ushort_t* __restrict__ h3,
                                              const float* __restrict__ wproj,
                                              float* __restrict__ proj) {
    __shared__ float wl[COUT*HID];                // 64 KB
    const int tid = threadIdx.x;
    const int bb  = blockIdx.y;
    const int pos = blockIdx.x * 256 + tid;

    #pragma unroll
    for (int i = 0; i < COUT*HID/256; ++i) {
        int idx = i*256 + tid;
        wl[idx] = wproj[idx];
    }
    __syncthreads();

    float acc[COUT];
    #pragma unroll
    for (int o = 0; o < COUT; ++o) acc[o] = 0.f;

    for (int cc = 0; cc < 8; ++cc) {              // 8 chunks of 32 channels
        float xr[32];
        #pragma unroll
        for (int c = 0; c < 32; ++c) {
            int bc = bb*HID + cc*32 + c;
            float v = bf2f(h3[(size_t)bc * THW + pos]);
            xr[c] = fmaxf(fmaf(v, g_stats[SAL + bc], g_stats[SBE + bc]), 0.f);
        }
        #pragma unroll
        for (int o = 0; o < COUT; o += 2) {
            float a0 = acc[o], a1 = acc[o+1];
            const float4* w0 = (const float4*)&wl[ o   *HID + cc*32];
            const float4* w1 = (const float4*)&wl[(o+1)*HID + cc*32];
            #pragma unroll
            for (int c4 = 0; c4 < 8; ++c4) {
                float4 wq = w0[c4], wr = w1[c4];
                a0 = fmaf(wq.x, xr[c4*4+0], a0); a1 = fmaf(wr.x, xr[c4*4+0], a1);
                a0 = fmaf(wq.y, xr[c4*4+1], a0); a1 = fmaf(wr.y, xr[c4*4+1], a1);
                a0 = fmaf(wq.z, xr[c4*4+2], a0); a1 = fmaf(wr.z, xr[c4*4+2], a1);
                a0 = fmaf(wq.w, xr[c4*4+3], a0); a1 = fmaf(wr.w, xr[c4*4+3], a1);
            }
            acc[o] = a0; acc[o+1] = a1;
        }
    }
    const size_t obase = (size_t)bb * COUT * THW + pos;
    #pragma unroll
    for (int o = 0; o < COUT; ++o)
        proj[obase + (size_t)o * THW] = acc[o];
}

// ------------ final: norm(proj) + shortcut, 2x2 maxpool, f32 out --------------
__global__ __launch_bounds__(256) void k_final(const float* __restrict__ proj,
                                               const float* __restrict__ x,
                                               float* __restrict__ out, int b0) {
    const int idx = blockIdx.x * 256 + threadIdx.x;   // nb*1048576 range
    const int xx = idx & 31;
    const int yy = (idx >> 5) & 31;
    const int t  = (idx >> 10) & 15;
    const int bo = idx >> 14;                         // bb*64+o (local)
    const float a  = g_stats[SISP + bo];
    const float bb = -g_stats[SMP + bo] * a;
    const size_t lbase = (size_t)bo * THW + t*HW_;               // proj (local)
    const size_t gbase = (size_t)(b0*COUT + bo) * THW + t*HW_;   // x (global)

    float m = -3.4e38f;
    #pragma unroll
    for (int r = 0; r < 2; ++r) {
        size_t off = (size_t)(2*yy + r)*W_ + 2*xx;
        float2 p2 = *(const float2*)(proj + lbase + off);
        float2 x2 = *(const float2*)(x + gbase + off);
        float v0 = fmaf(p2.x, a, bb) + x2.x;
        float v1 = fmaf(p2.y, a, bb) + x2.y;
        m = fmaxf(m, fmaxf(v0, v1));
    }
    out[(size_t)b0 * COUT * T_ * 1024 + idx] = m;
}

extern "C" void kernel_launch(void* const* d_in, const int* in_sizes, int n_in,
                              void* d_out, int out_size, void* d_ws, size_t ws_size,
                              hipStream_t stream) {
    const float* x     = (const float*)d_in[0];
    const float* w1    = (const float*)d_in[1];
    const float* wdws  = (const float*)d_in[2];
    const float* wdwt  = (const float*)d_in[3];
    const float* wse1  = (const float*)d_in[4];
    const float* wse2  = (const float*)d_in[5];
    const float* wproj = (const float*)d_in[6];
    float* out = (float*)d_out;

    // per-batch footprint: h1 32MB + h2 32MB (proj fp32 16MB reuses h2 region)
    const size_t perb = 2ull * HID * THW * sizeof(ushort_t);   // 64 MB
    int nb = (ws_size >= 4*perb) ? 4 : (ws_size >= 2*perb) ? 2 : 1;

    for (int b0 = 0; b0 < B_; b0 += nb) {
        char* ws = (char*)d_ws;
        ushort_t* h1   = (ushort_t*)ws;                              // nb*32 MB
        ushort_t* h2   = (ushort_t*)(ws + (size_t)nb * HID*THW*2);   // nb*32 MB
        ushort_t* h3   = h1;                                         // reuse
        float*    proj = (float*)h2;                                 // reuse (16MB/b <= 32MB/b)

        k_expand    <<<dim3(THW/256, nb), 256, 0, stream>>>(x, w1, h1, b0);
        k_stats_bf16<<<nb*HID, 256, 0, stream>>>(h1, SM1, SIS1);
        k_dws       <<<dim3(H_/4, T_, nb*HID), dim3(64,4), 0, stream>>>(h1, wdws, h2);
        k_stats_bf16<<<nb*HID, 256, 0, stream>>>(h2, SM2, SIS2);
        k_dwt       <<<dim3(HW_/256, T_, nb*HID), 256, 0, stream>>>(h2, wdwt, h3);
        k_stats_bf16<<<nb*HID, 256, 0, stream>>>(h3, SM3, SIS3);
        k_semean    <<<nb*HID, 256, 0, stream>>>(h3);
        k_semlp     <<<nb, 256, 0, stream>>>(wse1, wse2);
        k_proj      <<<dim3(THW/256, nb), 256, 0, stream>>>(h3, wproj, proj);
        k_stats_f32 <<<nb*COUT, 256, 0, stream>>>(proj, SMP, SISP);
        k_final     <<<nb*COUT*T_*1024/256, 256, 0, stream>>>(proj, x, out, b0);
    }
}

// Round 4
// 808.702 us; speedup vs baseline: 1.6151x; 1.6151x over previous
//
#include <hip/hip_runtime.h>
#include <hip/hip_bf16.h>

#define B_   4
#define CIN  64
#define HID  256
#define COUT 64
#define T_   16
#define H_   64
#define W_   64
#define HW_  (H_*W_)       // 4096
#define THW  (T_*HW_)      // 65536
#define EPS  1e-5f

typedef unsigned short ushort_t;
typedef unsigned int   uint_t;
typedef short bf16x8 __attribute__((ext_vector_type(8)));
typedef float f32x4  __attribute__((ext_vector_type(4)));

// ---- stats live in static device memory (NOT d_ws) ---------------------------
#define SM1   0
#define SIS1  1024
#define SM2   2048
#define SIS2  3072
#define SM3   4096
#define SIS3  5120
#define SSES  6144
#define SAL   7168
#define SBE   8192
#define SMP   9216
#define SISP  9472
__device__ float g_stats[10240];

__device__ __forceinline__ float bf2f(ushort_t u) {
    return __uint_as_float(((uint_t)u) << 16);
}
__device__ __forceinline__ ushort_t f2bf(float f) {
    uint_t u = __float_as_uint(f);
    uint_t r = u + 0x7fffu + ((u >> 16) & 1u);   // round-to-nearest-even
    return (ushort_t)(r >> 16);
}

// ============ expand 1x1 via MFMA: h1[o][n] = sum_k w1[o][k] * x[k][n] ========
// block: 256 thr = 4 waves; tile [O=256 x N=64], K=64 (2 K-steps of 32)
// wave w covers o in [w*64, w*64+64)
__global__ __launch_bounds__(256) void k_expand(const float* __restrict__ x,
                                                const float* __restrict__ w1,
                                                ushort_t* __restrict__ h1, int b0) {
    __shared__ ushort_t As[256*72];      // A[o][k], stride 72 (b128 reads at BW floor)
    __shared__ ushort_t Bs[64*72];       // B[k][n], stride 72, n rotated by 16*((k>>3)&3)
    const int tid = threadIdx.x;
    const int bb  = blockIdx.y, gb = b0 + bb;
    const int pos0 = blockIdx.x * 64;
    const int lane = tid & 63, wv = tid >> 6;
    const int q = lane >> 4, ln = lane & 15;

    // stage A: w1 [256 o x 64 k] fp32 -> bf16
    #pragma unroll
    for (int i = 0; i < 64; ++i) {
        int linear = i*256 + tid;
        int o = linear >> 6, k = linear & 63;
        As[o*72 + k] = f2bf(w1[linear]);
    }
    // stage B: x [64 k x 64 n] fp32 -> bf16, rotated columns
    #pragma unroll
    for (int i = 0; i < 16; ++i) {
        int linear = i*256 + tid;
        int k = linear >> 6, n = linear & 63;
        float v = x[(size_t)(gb*CIN + k) * THW + pos0 + n];
        Bs[k*72 + ((n + 16*((k>>3)&3)) & 63)] = f2bf(v);
    }
    __syncthreads();

    f32x4 acc[4][4];
    #pragma unroll
    for (int i = 0; i < 4; ++i)
        #pragma unroll
        for (int j = 0; j < 4; ++j)
            acc[i][j] = (f32x4){0.f,0.f,0.f,0.f};

    #pragma unroll
    for (int ks = 0; ks < 2; ++ks) {
        bf16x8 af[4];
        #pragma unroll
        for (int ot = 0; ot < 4; ++ot) {
            int o = wv*64 + ot*16 + ln;
            af[ot] = *(const bf16x8*)&As[o*72 + ks*32 + q*8];
        }
        bf16x8 bf[4];
        #pragma unroll
        for (int nt = 0; nt < 4; ++nt) {
            union { short s[8]; bf16x8 v; } bu;
            #pragma unroll
            for (int j = 0; j < 8; ++j) {
                int k = ks*32 + q*8 + j;
                int nn = (nt*16 + ln + 16*((k>>3)&3)) & 63;
                bu.s[j] = (short)Bs[k*72 + nn];
            }
            bf[nt] = bu.v;
        }
        #pragma unroll
        for (int ot = 0; ot < 4; ++ot)
            #pragma unroll
            for (int nt = 0; nt < 4; ++nt)
                acc[ot][nt] = __builtin_amdgcn_mfma_f32_16x16x32_bf16(
                    af[ot], bf[nt], acc[ot][nt], 0, 0, 0);
    }

    // epilogue: C/D layout col=lane&15 -> n, row=q*4+r -> o
    #pragma unroll
    for (int ot = 0; ot < 4; ++ot)
        #pragma unroll
        for (int nt = 0; nt < 4; ++nt)
            #pragma unroll
            for (int r = 0; r < 4; ++r) {
                int o = wv*64 + ot*16 + q*4 + r;
                int n = nt*16 + ln;
                h1[((size_t)bb*HID + o)*THW + pos0 + n] = f2bf(acc[ot][nt][r]);
            }
}

// ============ proj 1x1 via MFMA: proj[o][n] = sum_k wp[o][k] * xn[k][n] =======
// xn[k][n] = max(0, h3[k][n]*alpha[k] + beta[k])  (norm3+relu+SE folded)
// block: 256 thr = 4 waves; tile [O=64 x N=128], K=256 (4 chunks of 64)
// wave w covers n in [w*32, w*32+32)
__global__ __launch_bounds__(256) void k_proj(const ushort_t* __restrict__ h3,
                                              const float* __restrict__ wproj,
                                              float* __restrict__ proj) {
    __shared__ ushort_t As[64*264];      // A[o][k], stride 264
    __shared__ ushort_t Bs[64*136];      // B[klocal][n], stride 136, rotated cols
    const int tid = threadIdx.x;
    const int bb  = blockIdx.y;
    const int pos0 = blockIdx.x * 128;
    const int lane = tid & 63, wv = tid >> 6;
    const int q = lane >> 4, ln = lane & 15;

    // stage A: wproj [64 o x 256 k] fp32 -> bf16
    #pragma unroll
    for (int i = 0; i < 64; ++i) {
        int linear = i*256 + tid;
        int o = linear >> 8, k = linear & 255;
        As[o*264 + k] = f2bf(wproj[linear]);
    }

    f32x4 acc[4][2];
    #pragma unroll
    for (int i = 0; i < 4; ++i) {
        acc[i][0] = (f32x4){0.f,0.f,0.f,0.f};
        acc[i][1] = (f32x4){0.f,0.f,0.f,0.f};
    }

    for (int kc = 0; kc < 4; ++kc) {
        // stage B chunk: [64 k x 128 n] with alpha/beta/relu applied
        #pragma unroll
        for (int i = 0; i < 32; ++i) {
            int linear = i*256 + tid;
            int kl = linear >> 7, n = linear & 127;
            int ch = bb*HID + kc*64 + kl;
            float raw = bf2f(h3[(size_t)ch * THW + pos0 + n]);
            float v = fmaxf(fmaf(raw, g_stats[SAL + ch], g_stats[SBE + ch]), 0.f);
            Bs[kl*136 + ((n + 16*((kl>>3)&7)) & 127)] = f2bf(v);
        }
        __syncthreads();

        #pragma unroll
        for (int ks = 0; ks < 2; ++ks) {
            int kg = kc*2 + ks;
            bf16x8 af[4];
            #pragma unroll
            for (int ot = 0; ot < 4; ++ot) {
                int o = ot*16 + ln;
                af[ot] = *(const bf16x8*)&As[o*264 + kg*32 + q*8];
            }
            bf16x8 bf[2];
            #pragma unroll
            for (int nt = 0; nt < 2; ++nt) {
                union { short s[8]; bf16x8 v; } bu;
                #pragma unroll
                for (int j = 0; j < 8; ++j) {
                    int kl = ks*32 + q*8 + j;
                    int nn = (wv*32 + nt*16 + ln + 16*((kl>>3)&7)) & 127;
                    bu.s[j] = (short)Bs[kl*136 + nn];
                }
                bf[nt] = bu.v;
            }
            #pragma unroll
            for (int ot = 0; ot < 4; ++ot)
                #pragma unroll
                for (int nt = 0; nt < 2; ++nt)
                    acc[ot][nt] = __builtin_amdgcn_mfma_f32_16x16x32_bf16(
                        af[ot], bf[nt], acc[ot][nt], 0, 0, 0);
        }
        __syncthreads();
    }

    // epilogue: fp32 stores to proj[o][pos]
    #pragma unroll
    for (int ot = 0; ot < 4; ++ot)
        #pragma unroll
        for (int nt = 0; nt < 2; ++nt)
            #pragma unroll
            for (int r = 0; r < 4; ++r) {
                int o = ot*16 + q*4 + r;
                int n = wv*32 + nt*16 + ln;
                proj[((size_t)bb*COUT + o)*THW + pos0 + n] = acc[ot][nt][r];
            }
}

// ---------------- per-(bb,c) mean / inv_sd over THW, bf16 source --------------
__global__ __launch_bounds__(256) void k_stats_bf16(const ushort_t* __restrict__ src,
                                                    int moff, int isoff) {
    const int bc = blockIdx.x;
    const int tid = threadIdx.x;
    const ushort_t* p = src + (size_t)bc * THW;
    float s = 0.f, ss = 0.f;
    #pragma unroll 4
    for (int i = 0; i < THW/(256*8); ++i) {       // 32 iters, 16B/lane
        uint4 u = *(const uint4*)(p + i*2048 + tid*8);
        uint_t w[4] = {u.x, u.y, u.z, u.w};
        #pragma unroll
        for (int j = 0; j < 4; ++j) {
            float f0 = __uint_as_float(w[j] << 16);
            float f1 = __uint_as_float(w[j] & 0xffff0000u);
            s += f0; ss = fmaf(f0, f0, ss);
            s += f1; ss = fmaf(f1, f1, ss);
        }
    }
    #pragma unroll
    for (int off = 32; off > 0; off >>= 1) {
        s  += __shfl_down(s,  off, 64);
        ss += __shfl_down(ss, off, 64);
    }
    __shared__ float ls[4], lss[4];
    int wid = tid >> 6, lane = tid & 63;
    if (lane == 0) { ls[wid] = s; lss[wid] = ss; }
    __syncthreads();
    if (tid == 0) {
        float st  = ls[0]+ls[1]+ls[2]+ls[3];
        float sst = lss[0]+lss[1]+lss[2]+lss[3];
        float m = st * (1.f/THW);
        float v = sst * (1.f/THW) - m*m;
        g_stats[moff  + bc] = m;
        g_stats[isoff + bc] = 1.f / sqrtf(v + EPS);
    }
}

// ---------------- same, fp32 source (proj stats) ------------------------------
__global__ __launch_bounds__(256) void k_stats_f32(const float* __restrict__ src,
                                                   int moff, int isoff) {
    const int bc = blockIdx.x;
    const int tid = threadIdx.x;
    const float* p = src + (size_t)bc * THW;
    float s = 0.f, ss = 0.f;
    #pragma unroll 4
    for (int i = 0; i < THW/(256*4); ++i) {       // 64 iters
        float4 u = *(const float4*)(p + i*1024 + tid*4);
        s += u.x; ss = fmaf(u.x, u.x, ss);
        s += u.y; ss = fmaf(u.y, u.y, ss);
        s += u.z; ss = fmaf(u.z, u.z, ss);
        s += u.w; ss = fmaf(u.w, u.w, ss);
    }
    #pragma unroll
    for (int off = 32; off > 0; off >>= 1) {
        s  += __shfl_down(s,  off, 64);
        ss += __shfl_down(ss, off, 64);
    }
    __shared__ float ls[4], lss[4];
    int wid = tid >> 6, lane = tid & 63;
    if (lane == 0) { ls[wid] = s; lss[wid] = ss; }
    __syncthreads();
    if (tid == 0) {
        float st  = ls[0]+ls[1]+ls[2]+ls[3];
        float sst = lss[0]+lss[1]+lss[2]+lss[3];
        float m = st * (1.f/THW);
        float v = sst * (1.f/THW) - m*m;
        g_stats[moff  + bc] = m;
        g_stats[isoff + bc] = 1.f / sqrtf(v + EPS);
    }
}

// ------------ spatial dw 3x3 (+TIM fold, + stage1 norm/relu on the fly) -------
__global__ __launch_bounds__(256) void k_dws(const ushort_t* __restrict__ h1,
                                             const float* __restrict__ wdw,
                                             ushort_t* __restrict__ h2) {
    const int tx = threadIdx.x;                   // 0..63 (W)
    const int ty = threadIdx.y;                   // 0..3
    const int y  = blockIdx.x * 4 + ty;
    const int t  = blockIdx.y;
    const int bc = blockIdx.z;
    const int o  = bc & (HID-1);
    const size_t outidx = (size_t)bc * THW + t*HW_ + y*W_ + tx;

    // TIM: o<32 -> read t+1 (zero at t==15); 32<=o<64 -> zero; else identity
    int ts = t; bool zero = false;
    if (o < 32)       { ts = t + 1; if (ts >= T_) zero = true; }
    else if (o < 64)  { zero = true; }
    if (zero) { h2[outidx] = 0; return; }

    const float a  = g_stats[SIS1 + bc];
    const float bb = -g_stats[SM1 + bc] * a;
    const ushort_t* sp = h1 + (size_t)bc * THW + ts*HW_;

    float wf[9];
    #pragma unroll
    for (int k = 0; k < 9; ++k) wf[k] = wdw[o*9 + k];

    float acc = 0.f;
    #pragma unroll
    for (int dy = -1; dy <= 1; ++dy) {
        int yy = y + dy;
        if (yy < 0 || yy >= H_) continue;
        #pragma unroll
        for (int dx = -1; dx <= 1; ++dx) {
            int xx = tx + dx;
            if (xx < 0 || xx >= W_) continue;
            float v = fmaxf(fmaf(bf2f(sp[yy*W_ + xx]), a, bb), 0.f);
            acc = fmaf(wf[(dy+1)*3 + (dx+1)], v, acc);
        }
    }
    h2[outidx] = f2bf(acc);
}

// ------------ temporal dw 3 (+ stage2 norm/relu on the fly) -------------------
__global__ __launch_bounds__(256) void k_dwt(const ushort_t* __restrict__ h2,
                                             const float* __restrict__ wdt,
                                             ushort_t* __restrict__ h3) {
    const int tid = threadIdx.x;
    const int pos = blockIdx.x * 256 + tid;       // 0..4095 within slice
    const int t   = blockIdx.y;
    const int bc  = blockIdx.z;
    const int o   = bc & (HID-1);
    const float a  = g_stats[SIS2 + bc];
    const float bb = -g_stats[SM2 + bc] * a;
    const ushort_t* sp = h2 + (size_t)bc * THW;

    float acc = 0.f;
    #pragma unroll
    for (int dt = -1; dt <= 1; ++dt) {
        int tt = t + dt;
        if (tt < 0 || tt >= T_) continue;
        float v = fmaxf(fmaf(bf2f(sp[tt*HW_ + pos]), a, bb), 0.f);
        acc = fmaf(wdt[o*3 + dt + 1], v, acc);
    }
    h3[(size_t)bc*THW + t*HW_ + pos] = f2bf(acc);
}

// ------------ SE: per-(bb,c) mean of relu(norm3(h3)) --------------------------
__global__ __launch_bounds__(256) void k_semean(const ushort_t* __restrict__ h3) {
    const int bc = blockIdx.x;
    const int tid = threadIdx.x;
    const float a  = g_stats[SIS3 + bc];
    const float bb = -g_stats[SM3 + bc] * a;
    const ushort_t* p = h3 + (size_t)bc * THW;
    float s = 0.f;
    #pragma unroll 4
    for (int i = 0; i < THW/(256*8); ++i) {
        uint4 u = *(const uint4*)(p + i*2048 + tid*8);
        uint_t w[4] = {u.x, u.y, u.z, u.w};
        #pragma unroll
        for (int j = 0; j < 4; ++j) {
            s += fmaxf(fmaf(__uint_as_float(w[j] << 16),          a, bb), 0.f);
            s += fmaxf(fmaf(__uint_as_float(w[j] & 0xffff0000u),  a, bb), 0.f);
        }
    }
    #pragma unroll
    for (int off = 32; off > 0; off >>= 1) s += __shfl_down(s, off, 64);
    __shared__ float ls[4];
    int wid = tid >> 6, lane = tid & 63;
    if (lane == 0) ls[wid] = s;
    __syncthreads();
    if (tid == 0) g_stats[SSES + bc] = (ls[0]+ls[1]+ls[2]+ls[3]) * (1.f/THW);
}

// ------------ SE MLP -> fold sigmoid scale into proj's alpha/beta -------------
__global__ __launch_bounds__(256) void k_semlp(const float* __restrict__ wse1,
                                               const float* __restrict__ wse2) {
    __shared__ float mv[HID];
    __shared__ float y1[64];
    const int bb = blockIdx.x, tid = threadIdx.x;
    mv[tid] = g_stats[SSES + bb*HID + tid];
    __syncthreads();
    if (tid < 64) {
        float acc = 0.f;
        #pragma unroll 8
        for (int c = 0; c < HID; ++c) acc = fmaf(wse1[tid*HID + c], mv[c], acc);
        y1[tid] = fmaxf(acc, 0.f);
    }
    __syncthreads();
    float z = 0.f;
    #pragma unroll
    for (int c = 0; c < 64; ++c) z = fmaf(wse2[tid*64 + c], y1[c], z);
    float se = 1.f / (1.f + expf(-z));
    const int bc = bb*HID + tid;
    float al = g_stats[SIS3 + bc] * se;            // relu(norm)*se == max(0, h*al+be)
    g_stats[SAL + bc] = al;
    g_stats[SBE + bc] = -g_stats[SM3 + bc] * al;
}

// ------------ final: norm(proj) + shortcut, 2x2 maxpool, f32 out --------------
__global__ __launch_bounds__(256) void k_final(const float* __restrict__ proj,
                                               const float* __restrict__ x,
                                               float* __restrict__ out, int b0) {
    const int idx = blockIdx.x * 256 + threadIdx.x;   // nb*1048576 range
    const int xx = idx & 31;
    const int yy = (idx >> 5) & 31;
    const int t  = (idx >> 10) & 15;
    const int bo = idx >> 14;                         // bb*64+o (local)
    const float a  = g_stats[SISP + bo];
    const float bb = -g_stats[SMP + bo] * a;
    const size_t lbase = (size_t)bo * THW + t*HW_;               // proj (local)
    const size_t gbase = (size_t)(b0*COUT + bo) * THW + t*HW_;   // x (global)

    float m = -3.4e38f;
    #pragma unroll
    for (int r = 0; r < 2; ++r) {
        size_t off = (size_t)(2*yy + r)*W_ + 2*xx;
        float2 p2 = *(const float2*)(proj + lbase + off);
        float2 x2 = *(const float2*)(x + gbase + off);
        float v0 = fmaf(p2.x, a, bb) + x2.x;
        float v1 = fmaf(p2.y, a, bb) + x2.y;
        m = fmaxf(m, fmaxf(v0, v1));
    }
    out[(size_t)b0 * COUT * T_ * 1024 + idx] = m;
}

extern "C" void kernel_launch(void* const* d_in, const int* in_sizes, int n_in,
                              void* d_out, int out_size, void* d_ws, size_t ws_size,
                              hipStream_t stream) {
    const float* x     = (const float*)d_in[0];
    const float* w1    = (const float*)d_in[1];
    const float* wdws  = (const float*)d_in[2];
    const float* wdwt  = (const float*)d_in[3];
    const float* wse1  = (const float*)d_in[4];
    const float* wse2  = (const float*)d_in[5];
    const float* wproj = (const float*)d_in[6];
    float* out = (float*)d_out;

    // per-batch footprint: h1 32MB + h2 32MB (proj fp32 16MB reuses h2 region)
    const size_t perb = 2ull * HID * THW * sizeof(ushort_t);   // 64 MB
    int nb = (ws_size >= 4*perb) ? 4 : (ws_size >= 2*perb) ? 2 : 1;

    for (int b0 = 0; b0 < B_; b0 += nb) {
        char* ws = (char*)d_ws;
        ushort_t* h1   = (ushort_t*)ws;                              // nb*32 MB
        ushort_t* h2   = (ushort_t*)(ws + (size_t)nb * HID*THW*2);   // nb*32 MB
        ushort_t* h3   = h1;                                         // reuse
        float*    proj = (float*)h2;                                 // reuse (16MB/b <= 32MB/b)

        k_expand    <<<dim3(THW/64, nb), 256, 0, stream>>>(x, w1, h1, b0);
        k_stats_bf16<<<nb*HID, 256, 0, stream>>>(h1, SM1, SIS1);
        k_dws       <<<dim3(H_/4, T_, nb*HID), dim3(64,4), 0, stream>>>(h1, wdws, h2);
        k_stats_bf16<<<nb*HID, 256, 0, stream>>>(h2, SM2, SIS2);
        k_dwt       <<<dim3(HW_/256, T_, nb*HID), 256, 0, stream>>>(h2, wdwt, h3);
        k_stats_bf16<<<nb*HID, 256, 0, stream>>>(h3, SM3, SIS3);
        k_semean    <<<nb*HID, 256, 0, stream>>>(h3);
        k_semlp     <<<nb, 256, 0, stream>>>(wse1, wse2);
        k_proj      <<<dim3(THW/128, nb), 256, 0, stream>>>(h3, wproj, proj);
        k_stats_f32 <<<nb*COUT, 256, 0, stream>>>(proj, SMP, SISP);
        k_final     <<<nb*COUT*T_*1024/256, 256, 0, stream>>>(proj, x, out, b0);
    }
}

// Round 5
// 444.056 us; speedup vs baseline: 2.9414x; 1.8212x over previous
//
#include <hip/hip_runtime.h>
#include <hip/hip_bf16.h>

#define B_   4
#define CIN  64
#define HID  256
#define COUT 64
#define T_   16
#define H_   64
#define W_   64
#define HW_  (H_*W_)       // 4096
#define THW  (T_*HW_)      // 65536
#define EPS  1e-5f

typedef unsigned short ushort_t;
typedef unsigned int   uint_t;
typedef short bf16x8 __attribute__((ext_vector_type(8)));
typedef float f32x4  __attribute__((ext_vector_type(4)));

// ---- stats live in static device memory (NOT d_ws) ---------------------------
#define SM1   0
#define SIS1  1024
#define SM2   2048
#define SIS2  3072
#define SM3   4096
#define SIS3  5120
#define SSES  6144
#define SAL   7168
#define SBE   8192
#define SMP   9216
#define SISP  9472
__device__ float g_stats[10240];

__device__ __forceinline__ float bf2f(ushort_t u) {
    return __uint_as_float(((uint_t)u) << 16);
}
__device__ __forceinline__ ushort_t f2bf(float f) {
    uint_t u = __float_as_uint(f);
    uint_t r = u + 0x7fffu + ((u >> 16) & 1u);   // round-to-nearest-even
    return (ushort_t)(r >> 16);
}
// load 8 bf16 and apply max(0, v*a+bb)
__device__ __forceinline__ void loadnorm8(const ushort_t* p, float a, float bb,
                                          float* v) {
    uint4 u = *(const uint4*)p;
    uint_t uu[4] = {u.x, u.y, u.z, u.w};
    #pragma unroll
    for (int j = 0; j < 4; ++j) {
        v[2*j]   = fmaxf(fmaf(__uint_as_float(uu[j] << 16),         a, bb), 0.f);
        v[2*j+1] = fmaxf(fmaf(__uint_as_float(uu[j] & 0xffff0000u), a, bb), 0.f);
    }
}

// ============ expand 1x1 via MFMA: h1[o][n] = sum_k w1[o][k] * x[k][n] ========
__global__ __launch_bounds__(256) void k_expand(const float* __restrict__ x,
                                                const float* __restrict__ w1,
                                                ushort_t* __restrict__ h1, int b0) {
    __shared__ ushort_t As[256*72];      // A[o][k], stride 72
    __shared__ ushort_t Bs[64*72];       // B[k][n], stride 72, rotated cols
    const int tid = threadIdx.x;
    const int bb  = blockIdx.y, gb = b0 + bb;
    const int pos0 = blockIdx.x * 64;
    const int lane = tid & 63, wv = tid >> 6;
    const int q = lane >> 4, ln = lane & 15;

    #pragma unroll
    for (int i = 0; i < 64; ++i) {
        int linear = i*256 + tid;
        int o = linear >> 6, k = linear & 63;
        As[o*72 + k] = f2bf(w1[linear]);
    }
    #pragma unroll
    for (int i = 0; i < 16; ++i) {
        int linear = i*256 + tid;
        int k = linear >> 6, n = linear & 63;
        float v = x[(size_t)(gb*CIN + k) * THW + pos0 + n];
        Bs[k*72 + ((n + 16*((k>>3)&3)) & 63)] = f2bf(v);
    }
    __syncthreads();

    f32x4 acc[4][4];
    #pragma unroll
    for (int i = 0; i < 4; ++i)
        #pragma unroll
        for (int j = 0; j < 4; ++j)
            acc[i][j] = (f32x4){0.f,0.f,0.f,0.f};

    #pragma unroll
    for (int ks = 0; ks < 2; ++ks) {
        bf16x8 af[4];
        #pragma unroll
        for (int ot = 0; ot < 4; ++ot) {
            int o = wv*64 + ot*16 + ln;
            af[ot] = *(const bf16x8*)&As[o*72 + ks*32 + q*8];
        }
        bf16x8 bfr[4];
        #pragma unroll
        for (int nt = 0; nt < 4; ++nt) {
            union { short s[8]; bf16x8 v; } bu;
            #pragma unroll
            for (int j = 0; j < 8; ++j) {
                int k = ks*32 + q*8 + j;
                int nn = (nt*16 + ln + 16*((k>>3)&3)) & 63;
                bu.s[j] = (short)Bs[k*72 + nn];
            }
            bfr[nt] = bu.v;
        }
        #pragma unroll
        for (int ot = 0; ot < 4; ++ot)
            #pragma unroll
            for (int nt = 0; nt < 4; ++nt)
                acc[ot][nt] = __builtin_amdgcn_mfma_f32_16x16x32_bf16(
                    af[ot], bfr[nt], acc[ot][nt], 0, 0, 0);
    }

    #pragma unroll
    for (int ot = 0; ot < 4; ++ot)
        #pragma unroll
        for (int nt = 0; nt < 4; ++nt)
            #pragma unroll
            for (int r = 0; r < 4; ++r) {
                int o = wv*64 + ot*16 + q*4 + r;
                int n = nt*16 + ln;
                h1[((size_t)bb*HID + o)*THW + pos0 + n] = f2bf(acc[ot][nt][r]);
            }
}

// ============ proj 1x1 via MFMA (norm3+relu+SE folded into B staging) =========
__global__ __launch_bounds__(256) void k_proj(const ushort_t* __restrict__ h3,
                                              const float* __restrict__ wproj,
                                              float* __restrict__ proj) {
    __shared__ ushort_t As[64*264];      // A[o][k], stride 264
    __shared__ ushort_t Bs[64*136];      // B[klocal][n], stride 136, rotated cols
    const int tid = threadIdx.x;
    const int bb  = blockIdx.y;
    const int pos0 = blockIdx.x * 128;
    const int lane = tid & 63, wv = tid >> 6;
    const int q = lane >> 4, ln = lane & 15;

    #pragma unroll
    for (int i = 0; i < 64; ++i) {
        int linear = i*256 + tid;
        int o = linear >> 8, k = linear & 255;
        As[o*264 + k] = f2bf(wproj[linear]);
    }

    f32x4 acc[4][2];
    #pragma unroll
    for (int i = 0; i < 4; ++i) {
        acc[i][0] = (f32x4){0.f,0.f,0.f,0.f};
        acc[i][1] = (f32x4){0.f,0.f,0.f,0.f};
    }

    for (int kc = 0; kc < 4; ++kc) {
        #pragma unroll
        for (int i = 0; i < 32; ++i) {
            int linear = i*256 + tid;
            int kl = linear >> 7, n = linear & 127;
            int ch = bb*HID + kc*64 + kl;
            float raw = bf2f(h3[(size_t)ch * THW + pos0 + n]);
            float v = fmaxf(fmaf(raw, g_stats[SAL + ch], g_stats[SBE + ch]), 0.f);
            Bs[kl*136 + ((n + 16*((kl>>3)&7)) & 127)] = f2bf(v);
        }
        __syncthreads();

        #pragma unroll
        for (int ks = 0; ks < 2; ++ks) {
            int kg = kc*2 + ks;
            bf16x8 af[4];
            #pragma unroll
            for (int ot = 0; ot < 4; ++ot) {
                int o = ot*16 + ln;
                af[ot] = *(const bf16x8*)&As[o*264 + kg*32 + q*8];
            }
            bf16x8 bfr[2];
            #pragma unroll
            for (int nt = 0; nt < 2; ++nt) {
                union { short s[8]; bf16x8 v; } bu;
                #pragma unroll
                for (int j = 0; j < 8; ++j) {
                    int kl = ks*32 + q*8 + j;
                    int nn = (wv*32 + nt*16 + ln + 16*((kl>>3)&7)) & 127;
                    bu.s[j] = (short)Bs[kl*136 + nn];
                }
                bfr[nt] = bu.v;
            }
            #pragma unroll
            for (int ot = 0; ot < 4; ++ot)
                #pragma unroll
                for (int nt = 0; nt < 2; ++nt)
                    acc[ot][nt] = __builtin_amdgcn_mfma_f32_16x16x32_bf16(
                        af[ot], bfr[nt], acc[ot][nt], 0, 0, 0);
        }
        __syncthreads();
    }

    #pragma unroll
    for (int ot = 0; ot < 4; ++ot)
        #pragma unroll
        for (int nt = 0; nt < 2; ++nt)
            #pragma unroll
            for (int r = 0; r < 4; ++r) {
                int o = ot*16 + q*4 + r;
                int n = wv*32 + nt*16 + ln;
                proj[((size_t)bb*COUT + o)*THW + pos0 + n] = acc[ot][nt][r];
            }
}

// ---------------- per-(bb,c) mean / inv_sd over THW, bf16 source --------------
__global__ __launch_bounds__(256) void k_stats_bf16(const ushort_t* __restrict__ src,
                                                    int moff, int isoff) {
    const int bc = blockIdx.x;
    const int tid = threadIdx.x;
    const ushort_t* p = src + (size_t)bc * THW;
    float s = 0.f, ss = 0.f;
    #pragma unroll 4
    for (int i = 0; i < THW/(256*8); ++i) {       // 32 iters, 16B/lane
        uint4 u = *(const uint4*)(p + i*2048 + tid*8);
        uint_t w[4] = {u.x, u.y, u.z, u.w};
        #pragma unroll
        for (int j = 0; j < 4; ++j) {
            float f0 = __uint_as_float(w[j] << 16);
            float f1 = __uint_as_float(w[j] & 0xffff0000u);
            s += f0; ss = fmaf(f0, f0, ss);
            s += f1; ss = fmaf(f1, f1, ss);
        }
    }
    #pragma unroll
    for (int off = 32; off > 0; off >>= 1) {
        s  += __shfl_down(s,  off, 64);
        ss += __shfl_down(ss, off, 64);
    }
    __shared__ float ls[4], lss[4];
    int wid = tid >> 6, lane = tid & 63;
    if (lane == 0) { ls[wid] = s; lss[wid] = ss; }
    __syncthreads();
    if (tid == 0) {
        float st  = ls[0]+ls[1]+ls[2]+ls[3];
        float sst = lss[0]+lss[1]+lss[2]+lss[3];
        float m = st * (1.f/THW);
        float v = sst * (1.f/THW) - m*m;
        g_stats[moff  + bc] = m;
        g_stats[isoff + bc] = 1.f / sqrtf(v + EPS);
    }
}

// ---------------- same, fp32 source (proj stats) ------------------------------
__global__ __launch_bounds__(256) void k_stats_f32(const float* __restrict__ src,
                                                   int moff, int isoff) {
    const int bc = blockIdx.x;
    const int tid = threadIdx.x;
    const float* p = src + (size_t)bc * THW;
    float s = 0.f, ss = 0.f;
    #pragma unroll 4
    for (int i = 0; i < THW/(256*4); ++i) {       // 64 iters
        float4 u = *(const float4*)(p + i*1024 + tid*4);
        s += u.x; ss = fmaf(u.x, u.x, ss);
        s += u.y; ss = fmaf(u.y, u.y, ss);
        s += u.z; ss = fmaf(u.z, u.z, ss);
        s += u.w; ss = fmaf(u.w, u.w, ss);
    }
    #pragma unroll
    for (int off = 32; off > 0; off >>= 1) {
        s  += __shfl_down(s,  off, 64);
        ss += __shfl_down(ss, off, 64);
    }
    __shared__ float ls[4], lss[4];
    int wid = tid >> 6, lane = tid & 63;
    if (lane == 0) { ls[wid] = s; lss[wid] = ss; }
    __syncthreads();
    if (tid == 0) {
        float st  = ls[0]+ls[1]+ls[2]+ls[3];
        float sst = lss[0]+lss[1]+lss[2]+lss[3];
        float m = st * (1.f/THW);
        float v = sst * (1.f/THW) - m*m;
        g_stats[moff  + bc] = m;
        g_stats[isoff + bc] = 1.f / sqrtf(v + EPS);
    }
}

// ------------ spatial dw 3x3, 8-wide vectorized (+TIM, +norm1/relu) -----------
// block 256: thread -> (y = bid.x*32 + tid>>3, x0 = (tid&7)*8); 8 outputs/thread
__global__ __launch_bounds__(256) void k_dws(const ushort_t* __restrict__ h1,
                                             const float* __restrict__ wdw,
                                             ushort_t* __restrict__ h2) {
    const int tid = threadIdx.x;
    const int x0  = (tid & 7) * 8;
    const int y   = blockIdx.x * 32 + (tid >> 3);
    const int t   = blockIdx.y;
    const int bc  = blockIdx.z;
    const int o   = bc & (HID-1);
    const size_t outoff = (size_t)bc * THW + t*HW_ + y*W_ + x0;

    // TIM: o<32 -> read t+1 (zero at t==15); 32<=o<64 -> zero; else identity
    int ts = t; bool zero = false;
    if (o < 32)       { ts = t + 1; if (ts >= T_) zero = true; }
    else if (o < 64)  { zero = true; }
    if (zero) {
        uint4 z = {0u,0u,0u,0u};
        *(uint4*)(h2 + outoff) = z;
        return;
    }

    const float a  = g_stats[SIS1 + bc];
    const float bb = -g_stats[SM1 + bc] * a;
    const ushort_t* sp = h1 + (size_t)bc * THW + ts*HW_;

    float wf[9];
    #pragma unroll
    for (int k = 0; k < 9; ++k) wf[k] = wdw[o*9 + k];

    float v[3][10];                               // normalized input rows
    #pragma unroll
    for (int dy = 0; dy < 3; ++dy) {
        int yy = y + dy - 1;
        if (yy < 0 || yy >= H_) {
            #pragma unroll
            for (int j = 0; j < 10; ++j) v[dy][j] = 0.f;
        } else {
            const ushort_t* rp = sp + yy*W_;
            loadnorm8(rp + x0, a, bb, &v[dy][1]);
            v[dy][0] = (x0 == 0)  ? 0.f : fmaxf(fmaf(bf2f(rp[x0-1]), a, bb), 0.f);
            v[dy][9] = (x0 == 56) ? 0.f : fmaxf(fmaf(bf2f(rp[x0+8]), a, bb), 0.f);
        }
    }

    uint_t outp[4];
    #pragma unroll
    for (int i2 = 0; i2 < 4; ++i2) {
        float o0 = 0.f, o1 = 0.f;
        #pragma unroll
        for (int dy = 0; dy < 3; ++dy)
            #pragma unroll
            for (int dx = 0; dx < 3; ++dx) {
                float w = wf[dy*3+dx];
                o0 = fmaf(w, v[dy][2*i2 + dx],     o0);
                o1 = fmaf(w, v[dy][2*i2 + 1 + dx], o1);
            }
        outp[i2] = (uint_t)f2bf(o0) | ((uint_t)f2bf(o1) << 16);
    }
    uint4 r; r.x = outp[0]; r.y = outp[1]; r.z = outp[2]; r.w = outp[3];
    *(uint4*)(h2 + outoff) = r;
}

// ------------ temporal dw 3, 8-wide + rolling t-window (+norm2/relu) ----------
// thread owns 8 positions, loops t=0..15; each plane loaded+normalized once
__global__ __launch_bounds__(256) void k_dwt(const ushort_t* __restrict__ h2,
                                             const float* __restrict__ wdt,
                                             ushort_t* __restrict__ h3) {
    const int tid = threadIdx.x;
    const int pos = (blockIdx.x * 256 + tid) * 8;     // within HW_ slice
    const int bc  = blockIdx.y;
    const int o   = bc & (HID-1);
    const float a  = g_stats[SIS2 + bc];
    const float bb = -g_stats[SM2 + bc] * a;
    const float w0 = wdt[o*3+0], w1 = wdt[o*3+1], w2 = wdt[o*3+2];
    const ushort_t* sp = h2 + (size_t)bc * THW + pos;
    ushort_t*       op = h3 + (size_t)bc * THW + pos;

    float p[8], c[8], n[8];
    #pragma unroll
    for (int i = 0; i < 8; ++i) p[i] = 0.f;
    loadnorm8(sp,       a, bb, c);
    loadnorm8(sp + HW_, a, bb, n);

    #pragma unroll
    for (int t = 0; t < T_; ++t) {
        uint_t outp[4];
        #pragma unroll
        for (int i2 = 0; i2 < 4; ++i2) {
            float o0 = fmaf(w0, p[2*i2],   fmaf(w1, c[2*i2],   w2 * n[2*i2]));
            float o1 = fmaf(w0, p[2*i2+1], fmaf(w1, c[2*i2+1], w2 * n[2*i2+1]));
            outp[i2] = (uint_t)f2bf(o0) | ((uint_t)f2bf(o1) << 16);
        }
        uint4 r; r.x = outp[0]; r.y = outp[1]; r.z = outp[2]; r.w = outp[3];
        *(uint4*)(op + t*HW_) = r;

        #pragma unroll
        for (int i = 0; i < 8; ++i) { p[i] = c[i]; c[i] = n[i]; }
        if (t + 2 < T_) {
            loadnorm8(sp + (t+2)*HW_, a, bb, n);
        } else {
            #pragma unroll
            for (int i = 0; i < 8; ++i) n[i] = 0.f;
        }
    }
}

// ------------ SE: per-(bb,c) mean of relu(norm3(h3)) --------------------------
__global__ __launch_bounds__(256) void k_semean(const ushort_t* __restrict__ h3) {
    const int bc = blockIdx.x;
    const int tid = threadIdx.x;
    const float a  = g_stats[SIS3 + bc];
    const float bb = -g_stats[SM3 + bc] * a;
    const ushort_t* p = h3 + (size_t)bc * THW;
    float s = 0.f;
    #pragma unroll 4
    for (int i = 0; i < THW/(256*8); ++i) {
        uint4 u = *(const uint4*)(p + i*2048 + tid*8);
        uint_t w[4] = {u.x, u.y, u.z, u.w};
        #pragma unroll
        for (int j = 0; j < 4; ++j) {
            s += fmaxf(fmaf(__uint_as_float(w[j] << 16),          a, bb), 0.f);
            s += fmaxf(fmaf(__uint_as_float(w[j] & 0xffff0000u),  a, bb), 0.f);
        }
    }
    #pragma unroll
    for (int off = 32; off > 0; off >>= 1) s += __shfl_down(s, off, 64);
    __shared__ float ls[4];
    int wid = tid >> 6, lane = tid & 63;
    if (lane == 0) ls[wid] = s;
    __syncthreads();
    if (tid == 0) g_stats[SSES + bc] = (ls[0]+ls[1]+ls[2]+ls[3]) * (1.f/THW);
}

// ------------ SE MLP -> fold sigmoid scale into proj's alpha/beta -------------
__global__ __launch_bounds__(256) void k_semlp(const float* __restrict__ wse1,
                                               const float* __restrict__ wse2) {
    __shared__ float mv[HID];
    __shared__ float y1[64];
    const int bb = blockIdx.x, tid = threadIdx.x;
    mv[tid] = g_stats[SSES + bb*HID + tid];
    __syncthreads();
    if (tid < 64) {
        float acc = 0.f;
        #pragma unroll 8
        for (int c = 0; c < HID; ++c) acc = fmaf(wse1[tid*HID + c], mv[c], acc);
        y1[tid] = fmaxf(acc, 0.f);
    }
    __syncthreads();
    float z = 0.f;
    #pragma unroll
    for (int c = 0; c < 64; ++c) z = fmaf(wse2[tid*64 + c], y1[c], z);
    float se = 1.f / (1.f + expf(-z));
    const int bc = bb*HID + tid;
    float al = g_stats[SIS3 + bc] * se;            // relu(norm)*se == max(0, h*al+be)
    g_stats[SAL + bc] = al;
    g_stats[SBE + bc] = -g_stats[SM3 + bc] * al;
}

// ------------ final: norm(proj) + shortcut, 2x2 maxpool, f32 out --------------
__global__ __launch_bounds__(256) void k_final(const float* __restrict__ proj,
                                               const float* __restrict__ x,
                                               float* __restrict__ out, int b0) {
    const int idx = blockIdx.x * 256 + threadIdx.x;   // nb*1048576 range
    const int xx = idx & 31;
    const int yy = (idx >> 5) & 31;
    const int t  = (idx >> 10) & 15;
    const int bo = idx >> 14;                         // bb*64+o (local)
    const float a  = g_stats[SISP + bo];
    const float bb = -g_stats[SMP + bo] * a;
    const size_t lbase = (size_t)bo * THW + t*HW_;               // proj (local)
    const size_t gbase = (size_t)(b0*COUT + bo) * THW + t*HW_;   // x (global)

    float m = -3.4e38f;
    #pragma unroll
    for (int r = 0; r < 2; ++r) {
        size_t off = (size_t)(2*yy + r)*W_ + 2*xx;
        float2 p2 = *(const float2*)(proj + lbase + off);
        float2 x2 = *(const float2*)(x + gbase + off);
        float v0 = fmaf(p2.x, a, bb) + x2.x;
        float v1 = fmaf(p2.y, a, bb) + x2.y;
        m = fmaxf(m, fmaxf(v0, v1));
    }
    out[(size_t)b0 * COUT * T_ * 1024 + idx] = m;
}

extern "C" void kernel_launch(void* const* d_in, const int* in_sizes, int n_in,
                              void* d_out, int out_size, void* d_ws, size_t ws_size,
                              hipStream_t stream) {
    const float* x     = (const float*)d_in[0];
    const float* w1    = (const float*)d_in[1];
    const float* wdws  = (const float*)d_in[2];
    const float* wdwt  = (const float*)d_in[3];
    const float* wse1  = (const float*)d_in[4];
    const float* wse2  = (const float*)d_in[5];
    const float* wproj = (const float*)d_in[6];
    float* out = (float*)d_out;

    // per-batch footprint: h1 32MB + h2 32MB (proj fp32 16MB reuses h2 region)
    const size_t perb = 2ull * HID * THW * sizeof(ushort_t);   // 64 MB
    int nb = (ws_size >= 4*perb) ? 4 : (ws_size >= 2*perb) ? 2 : 1;

    for (int b0 = 0; b0 < B_; b0 += nb) {
        char* ws = (char*)d_ws;
        ushort_t* h1   = (ushort_t*)ws;                              // nb*32 MB
        ushort_t* h2   = (ushort_t*)(ws + (size_t)nb * HID*THW*2);   // nb*32 MB
        ushort_t* h3   = h1;                                         // reuse
        float*    proj = (float*)h2;                                 // reuse (16MB/b <= 32MB/b)

        k_expand    <<<dim3(THW/64, nb), 256, 0, stream>>>(x, w1, h1, b0);
        k_stats_bf16<<<nb*HID, 256, 0, stream>>>(h1, SM1, SIS1);
        k_dws       <<<dim3(2, T_, nb*HID), 256, 0, stream>>>(h1, wdws, h2);
        k_stats_bf16<<<nb*HID, 256, 0, stream>>>(h2, SM2, SIS2);
        k_dwt       <<<dim3(HW_/2048, nb*HID), 256, 0, stream>>>(h2, wdwt, h3);
        k_stats_bf16<<<nb*HID, 256, 0, stream>>>(h3, SM3, SIS3);
        k_semean    <<<nb*HID, 256, 0, stream>>>(h3);
        k_semlp     <<<nb, 256, 0, stream>>>(wse1, wse2);
        k_proj      <<<dim3(THW/128, nb), 256, 0, stream>>>(h3, wproj, proj);
        k_stats_f32 <<<nb*COUT, 256, 0, stream>>>(proj, SMP, SISP);
        k_final     <<<nb*COUT*T_*1024/256, 256, 0, stream>>>(proj, x, out, b0);
    }
}